// Round 1
// baseline (3070.020 us; speedup 1.0000x reference)
//
#include <hip/hip_runtime.h>
#include <math.h>

static constexpr int BB = 8;
static constexpr int KK = 16384;
static constexpr int CC = 256;
static constexpr int NPROP = 1024;
static constexpr int NSAMP = 16;
static constexpr int NH = 12;
static constexpr int NS = 18;
static constexpr int NCLS = 18;
static constexpr int DOUT = 119; // 2+3+2*NH+4*NS+NCLS

// d_out flat offsets (floats)
static constexpr int OFF_OBJ = 0;
static constexpr int OFF_CEN = OFF_OBJ + BB * NPROP * 2;
static constexpr int OFF_HS  = OFF_CEN + BB * NPROP * 3;
static constexpr int OFF_HR  = OFF_HS + BB * NPROP * NH;
static constexpr int OFF_SS  = OFF_HR + BB * NPROP * NH;
static constexpr int OFF_SR  = OFF_SS + BB * NPROP * NS;
static constexpr int OFF_SC  = OFF_SR + BB * NPROP * NS * 3;
static constexpr int OFF_FEAT = OFF_SC + BB * NPROP * NCLS;

// ---------------- weight transpose prep ----------------
__global__ void prep_weights(const float* __restrict__ W1, const float* __restrict__ W2,
                             const float* __restrict__ W3, const float* __restrict__ P1,
                             const float* __restrict__ P2, const float* __restrict__ P3,
                             float* __restrict__ W1T, float* __restrict__ W2T,
                             float* __restrict__ W3T, float* __restrict__ P1T,
                             float* __restrict__ P2T, float* __restrict__ P3T) {
    int i = blockIdx.x * 256 + threadIdx.x;
    if (i < 260 * 128) {  // W1T [260][128], rows 259 padded with 0
        int c = i >> 7, o = i & 127;
        W1T[i] = (c < 259) ? W1[o * 259 + c] : 0.f;
        return;
    }
    i -= 260 * 128;
    if (i < 16384) { int c = i >> 7, o = i & 127; W2T[i] = W2[o * 128 + c]; return; }
    i -= 16384;
    if (i < 16384) { int c = i >> 7, o = i & 127; W3T[i] = W3[o * 128 + c]; return; }
    i -= 16384;
    if (i < 16384) { int c = i >> 7, o = i & 127; P1T[i] = P1[o * 128 + c]; return; }
    i -= 16384;
    if (i < 16384) { int c = i >> 7, o = i & 127; P2T[i] = P2[o * 128 + c]; return; }
    i -= 16384;
    if (i < 128 * DOUT) { int c = i / DOUT, o = i % DOUT; P3T[i] = P3[o * 128 + c]; return; }
}

// ---------------- features [B,C,K] -> [B,K,C] ----------------
__global__ __launch_bounds__(256) void transpose_feat(const float* __restrict__ f,
                                                      float* __restrict__ fT) {
    __shared__ float tile[32][33];
    int b = blockIdx.z;
    int k0 = blockIdx.x * 32, c0 = blockIdx.y * 32;
    int tx = threadIdx.x, ty = threadIdx.y;
    const float* fb = f + (size_t)b * CC * KK;
#pragma unroll
    for (int i = 0; i < 4; i++) {
        int cl = ty + i * 8;
        tile[cl][tx] = fb[(size_t)(c0 + cl) * KK + k0 + tx];
    }
    __syncthreads();
    float* fTb = fT + (size_t)b * KK * CC;
#pragma unroll
    for (int i = 0; i < 4; i++) {
        int kl = ty + i * 8;
        fTb[(size_t)(k0 + kl) * CC + c0 + tx] = tile[tx][kl];
    }
}

// ---------------- FPS: 1 block per batch ----------------
__global__ __launch_bounds__(1024) void fps_kernel(const float* __restrict__ xyz,
                                                   int* __restrict__ fps_idx,
                                                   float* __restrict__ new_xyz) {
#pragma clang fp contract(off)
    int b = blockIdx.x;
    int tid = threadIdx.x;
    int lane = tid & 63, wid = tid >> 6;
    const float* xb = xyz + (size_t)b * KK * 3;

    float px[16], py[16], pz[16], dist[16];
#pragma unroll
    for (int j = 0; j < 16; j++) {
        int idx = j * 1024 + tid;
        px[j] = xb[idx * 3 + 0];
        py[j] = xb[idx * 3 + 1];
        pz[j] = xb[idx * 3 + 2];
        dist[j] = 1e10f;
    }
    __shared__ float redv[16];
    __shared__ int redi[16];
    __shared__ int curslot;
    int cur = 0;
    for (int t = 0; t < NPROP; t++) {
        float sx = xb[cur * 3 + 0];
        float sy = xb[cur * 3 + 1];
        float sz = xb[cur * 3 + 2];
        if (tid == 0) {
            fps_idx[b * NPROP + t] = cur;
            new_xyz[(b * NPROP + t) * 3 + 0] = sx;
            new_xyz[(b * NPROP + t) * 3 + 1] = sy;
            new_xyz[(b * NPROP + t) * 3 + 2] = sz;
        }
        float lmax = -1.f;
        int lidx = 0;
#pragma unroll
        for (int j = 0; j < 16; j++) {
            float dx = px[j] - sx;
            float dy = py[j] - sy;
            float dz = pz[j] - sz;
            float a = dx * dx;
            float bq = dy * dy;
            float cq = dz * dz;
            float d = (a + bq) + cq;        // numpy sum order, no fma
            float nd = dist[j] < d ? dist[j] : d;
            dist[j] = nd;
            if (nd > lmax) { lmax = nd; lidx = j * 1024 + tid; }
        }
        // wave reduce: max value, tie -> smallest index
#pragma unroll
        for (int m = 1; m < 64; m <<= 1) {
            float ov = __shfl_xor(lmax, m, 64);
            int oi = __shfl_xor(lidx, m, 64);
            if (ov > lmax || (ov == lmax && oi < lidx)) { lmax = ov; lidx = oi; }
        }
        if (lane == 0) { redv[wid] = lmax; redi[wid] = lidx; }
        __syncthreads();
        if (wid == 0) {
            float v = lane < 16 ? redv[lane] : -2.f;
            int i2 = lane < 16 ? redi[lane] : 0x7fffffff;
#pragma unroll
            for (int m = 1; m < 16; m <<= 1) {
                float ov = __shfl_xor(v, m, 64);
                int oi = __shfl_xor(i2, m, 64);
                if (ov > v || (ov == v && oi < i2)) { v = ov; i2 = oi; }
            }
            if (lane == 0) curslot = i2;
        }
        __syncthreads();
        cur = curslot;
    }
}

// ---------------- ball query: 1 wave per center ----------------
__global__ __launch_bounds__(256) void ballquery_kernel(const float* __restrict__ xyz,
                                                        const float* __restrict__ new_xyz,
                                                        int* __restrict__ bq) {
#pragma clang fp contract(off)
    int gid = blockIdx.x * 4 + (threadIdx.x >> 6);
    int lane = threadIdx.x & 63;
    int b = gid >> 10, p = gid & 1023;
    const float* xb = xyz + (size_t)b * KK * 3;
    float cx = new_xyz[(b * NPROP + p) * 3 + 0];
    float cy = new_xyz[(b * NPROP + p) * 3 + 1];
    float cz = new_xyz[(b * NPROP + p) * 3 + 2];
    const float R2 = (float)(0.3 * 0.3);
    int out_base = (b * NPROP + p) * NSAMP;
    int found = 0;
    int firsthit = -1;
    for (int base = 0; base < KK && found < NSAMP; base += 64) {
        int k = base + lane;
        float dx = cx - xb[k * 3 + 0];
        float dy = cy - xb[k * 3 + 1];
        float dz = cz - xb[k * 3 + 2];
        float a = dx * dx;
        float bb2 = dy * dy;
        float cc2 = dz * dz;
        float d2 = (a + bb2) + cc2;
        bool pred = d2 < R2;
        unsigned long long mask = __ballot(pred);
        int prefix = __popcll(mask & ((1ull << lane) - 1ull));
        if (pred) {
            int pos = found + prefix;
            if (pos < NSAMP) bq[out_base + pos] = k;
        }
        if (firsthit < 0 && mask) firsthit = base + (__ffsll(mask) - 1);
        found += __popcll(mask);
    }
    if (lane < NSAMP && lane >= found) bq[out_base + lane] = firsthit;
}

// ---------------- fused gather + MLP1-3 + maxpool + head + epilogue ----------------
__global__ __launch_bounds__(256) void fused_mlp(
    const float* __restrict__ fT, const float* __restrict__ xyz,
    const float* __restrict__ new_xyz, const int* __restrict__ bq,
    const float* __restrict__ W1T, const float* __restrict__ g1, const float* __restrict__ b1,
    const float* __restrict__ W2T, const float* __restrict__ g2, const float* __restrict__ b2,
    const float* __restrict__ W3T, const float* __restrict__ g3, const float* __restrict__ b3,
    const float* __restrict__ P1T, const float* __restrict__ pg1, const float* __restrict__ pb1,
    const float* __restrict__ P2T, const float* __restrict__ pg2, const float* __restrict__ pb2,
    const float* __restrict__ P3T, const float* __restrict__ pb3, const float* __restrict__ msa,
    float* __restrict__ out) {
    __shared__ float xs[16][260];
    __shared__ float hA[16][128];
    __shared__ float hB[16][128];
    __shared__ float pmax[8][128];
    __shared__ float featl[128];
    __shared__ float heada[128];
    __shared__ float headb[128];
    __shared__ int sidx[16];

    int tid = threadIdx.x;
    int blk = blockIdx.x;
    int b = blk >> 10, p = blk & 1023;
    int bp = b * NPROP + p;

    if (tid < 16) sidx[tid] = bq[bp * NSAMP + tid];
    float c0 = new_xyz[bp * 3 + 0];
    float c1 = new_xyz[bp * 3 + 1];
    float c2 = new_xyz[bp * 3 + 2];
    __syncthreads();

    // gather: xs[s] = [gxyz(3), feat(256), pad(1)]
    for (int s = 0; s < 16; s++) {
        int k = sidx[s];
        xs[s][3 + tid] = fT[((size_t)(b * KK + k)) * CC + tid];
        if (tid < 3) {
            float xv = xyz[((size_t)(b * KK + k)) * 3 + tid];
            float cv = (tid == 0) ? c0 : (tid == 1) ? c1 : c2;
            xs[s][tid] = (xv - cv) / 0.3f;
        }
        if (tid == 3) xs[s][259] = 0.f;
    }
    __syncthreads();

    int og = tid & 31, sg = tid >> 5;
    int o0 = og * 4, s0 = sg * 2;
    float acc[4][2];

    // ---- layer 1: K=260 (padded), in xs ----
#pragma unroll
    for (int oi = 0; oi < 4; oi++) { acc[oi][0] = 0.f; acc[oi][1] = 0.f; }
    for (int cg = 0; cg < 65; cg++) {
        int cb = cg * 4;
        float wv[4][4], xv[2][4];
#pragma unroll
        for (int j = 0; j < 4; j++)
            *(float4*)&wv[j][0] = *(const float4*)&W1T[(cb + j) * 128 + o0];
        *(float4*)&xv[0][0] = *(const float4*)&xs[s0][cb];
        *(float4*)&xv[1][0] = *(const float4*)&xs[s0 + 1][cb];
#pragma unroll
        for (int j = 0; j < 4; j++)
#pragma unroll
            for (int oi = 0; oi < 4; oi++) {
                acc[oi][0] += wv[j][oi] * xv[0][j];
                acc[oi][1] += wv[j][oi] * xv[1][j];
            }
    }
    {
        float ga[4], ba[4];
        *(float4*)ga = *(const float4*)&g1[o0];
        *(float4*)ba = *(const float4*)&b1[o0];
#pragma unroll
        for (int si = 0; si < 2; si++) {
            float tmp[4];
#pragma unroll
            for (int oi = 0; oi < 4; oi++)
                tmp[oi] = fmaxf(acc[oi][si] * ga[oi] + ba[oi], 0.f);
            *(float4*)&hA[s0 + si][o0] = *(float4*)tmp;
        }
    }
    __syncthreads();

    // ---- layer 2: K=128, in hA -> hB ----
#pragma unroll
    for (int oi = 0; oi < 4; oi++) { acc[oi][0] = 0.f; acc[oi][1] = 0.f; }
    for (int cg = 0; cg < 32; cg++) {
        int cb = cg * 4;
        float wv[4][4], xv[2][4];
#pragma unroll
        for (int j = 0; j < 4; j++)
            *(float4*)&wv[j][0] = *(const float4*)&W2T[(cb + j) * 128 + o0];
        *(float4*)&xv[0][0] = *(const float4*)&hA[s0][cb];
        *(float4*)&xv[1][0] = *(const float4*)&hA[s0 + 1][cb];
#pragma unroll
        for (int j = 0; j < 4; j++)
#pragma unroll
            for (int oi = 0; oi < 4; oi++) {
                acc[oi][0] += wv[j][oi] * xv[0][j];
                acc[oi][1] += wv[j][oi] * xv[1][j];
            }
    }
    {
        float ga[4], ba[4];
        *(float4*)ga = *(const float4*)&g2[o0];
        *(float4*)ba = *(const float4*)&b2[o0];
#pragma unroll
        for (int si = 0; si < 2; si++) {
            float tmp[4];
#pragma unroll
            for (int oi = 0; oi < 4; oi++)
                tmp[oi] = fmaxf(acc[oi][si] * ga[oi] + ba[oi], 0.f);
            *(float4*)&hB[s0 + si][o0] = *(float4*)tmp;
        }
    }
    __syncthreads();

    // ---- layer 3: K=128, in hB -> relu -> partial max -> pmax ----
#pragma unroll
    for (int oi = 0; oi < 4; oi++) { acc[oi][0] = 0.f; acc[oi][1] = 0.f; }
    for (int cg = 0; cg < 32; cg++) {
        int cb = cg * 4;
        float wv[4][4], xv[2][4];
#pragma unroll
        for (int j = 0; j < 4; j++)
            *(float4*)&wv[j][0] = *(const float4*)&W3T[(cb + j) * 128 + o0];
        *(float4*)&xv[0][0] = *(const float4*)&hB[s0][cb];
        *(float4*)&xv[1][0] = *(const float4*)&hB[s0 + 1][cb];
#pragma unroll
        for (int j = 0; j < 4; j++)
#pragma unroll
            for (int oi = 0; oi < 4; oi++) {
                acc[oi][0] += wv[j][oi] * xv[0][j];
                acc[oi][1] += wv[j][oi] * xv[1][j];
            }
    }
    {
        float ga[4], ba[4];
        *(float4*)ga = *(const float4*)&g3[o0];
        *(float4*)ba = *(const float4*)&b3[o0];
        float tmp[4];
#pragma unroll
        for (int oi = 0; oi < 4; oi++) {
            float v0 = fmaxf(acc[oi][0] * ga[oi] + ba[oi], 0.f);
            float v1 = fmaxf(acc[oi][1] * ga[oi] + ba[oi], 0.f);
            tmp[oi] = fmaxf(v0, v1);
        }
        *(float4*)&pmax[sg][o0] = *(float4*)tmp;
    }
    __syncthreads();

    // ---- maxpool over 16 samples ----
    if (tid < 128) {
        float m = pmax[0][tid];
#pragma unroll
        for (int s = 1; s < 8; s++) m = fmaxf(m, pmax[s][tid]);
        featl[tid] = m;
        out[OFF_FEAT + (size_t)bp * 128 + tid] = m;
    }
    __syncthreads();

    // ---- head layer 1 ----
    if (tid < 128) {
        float s = 0.f;
        for (int c = 0; c < 128; c++) s += P1T[c * 128 + tid] * featl[c];
        heada[tid] = fmaxf(s * pg1[tid] + pb1[tid], 0.f);
    }
    __syncthreads();
    // ---- head layer 2 ----
    if (tid < 128) {
        float s = 0.f;
        for (int c = 0; c < 128; c++) s += P2T[c * 128 + tid] * heada[c];
        headb[tid] = fmaxf(s * pg2[tid] + pb2[tid], 0.f);
    }
    __syncthreads();
    // ---- head layer 3 + epilogue ----
    if (tid < DOUT) {
        float s = 0.f;
        for (int c = 0; c < 128; c++) s += P3T[c * DOUT + tid] * headb[c];
        s += pb3[tid];
        if (tid < 2) {
            out[OFF_OBJ + (size_t)bp * 2 + tid] = s;
        } else if (tid < 5) {
            out[OFF_CEN + (size_t)bp * 3 + (tid - 2)] = new_xyz[bp * 3 + (tid - 2)] + s;
        } else if (tid < 17) {
            out[OFF_HS + (size_t)bp * NH + (tid - 5)] = s;
        } else if (tid < 29) {
            out[OFF_HR + (size_t)bp * NH + (tid - 17)] = s * (float)(M_PI / 12.0);
        } else if (tid < 47) {
            out[OFF_SS + (size_t)bp * NS + (tid - 29)] = s;
        } else if (tid < 101) {
            int j = tid - 47;
            out[OFF_SR + (size_t)bp * NS * 3 + j] = s * msa[j];
        } else {
            out[OFF_SC + (size_t)bp * NCLS + (tid - 101)] = s;
        }
    }
}

// ---------------- launch ----------------
extern "C" void kernel_launch(void* const* d_in, const int* in_sizes, int n_in,
                              void* d_out, int out_size, void* d_ws, size_t ws_size,
                              hipStream_t stream) {
    const float* xyz = (const float*)d_in[0];
    const float* features = (const float*)d_in[1];
    const float* W1 = (const float*)d_in[2];
    const float* g1 = (const float*)d_in[3];
    const float* b1 = (const float*)d_in[4];
    const float* W2 = (const float*)d_in[5];
    const float* g2 = (const float*)d_in[6];
    const float* b2 = (const float*)d_in[7];
    const float* W3 = (const float*)d_in[8];
    const float* g3 = (const float*)d_in[9];
    const float* b3 = (const float*)d_in[10];
    const float* P1 = (const float*)d_in[11];
    const float* pg1 = (const float*)d_in[12];
    const float* pb1 = (const float*)d_in[13];
    const float* P2 = (const float*)d_in[14];
    const float* pg2 = (const float*)d_in[15];
    const float* pb2 = (const float*)d_in[16];
    const float* P3 = (const float*)d_in[17];
    const float* pb3 = (const float*)d_in[18];
    const float* msa = (const float*)d_in[19];
    float* out = (float*)d_out;

    char* w = (char*)d_ws;
    float* W1T = (float*)w; w += (size_t)260 * 128 * 4;
    float* W2T = (float*)w; w += 16384 * 4;
    float* W3T = (float*)w; w += 16384 * 4;
    float* P1T = (float*)w; w += 16384 * 4;
    float* P2T = (float*)w; w += 16384 * 4;
    float* P3T = (float*)w; w += 16384 * 4;  // 15232 used, padded
    int* fps_i = (int*)w;  w += (size_t)BB * NPROP * 4;
    float* nxyz = (float*)w; w += (size_t)BB * NPROP * 3 * 4;
    int* bq = (int*)w;     w += (size_t)BB * NPROP * NSAMP * 4;
    float* fT = (float*)w; w += (size_t)BB * KK * CC * 4;

    int prep_elems = 260 * 128 + 16384 * 4 + 128 * DOUT;
    prep_weights<<<(prep_elems + 255) / 256, 256, 0, stream>>>(
        W1, W2, W3, P1, P2, P3, W1T, W2T, W3T, P1T, P2T, P3T);
    transpose_feat<<<dim3(KK / 32, CC / 32, BB), dim3(32, 8), 0, stream>>>(features, fT);
    fps_kernel<<<BB, 1024, 0, stream>>>(xyz, fps_i, nxyz);
    ballquery_kernel<<<(BB * NPROP) / 4, 256, 0, stream>>>(xyz, nxyz, bq);
    fused_mlp<<<BB * NPROP, 256, 0, stream>>>(
        fT, xyz, nxyz, bq,
        W1T, g1, b1, W2T, g2, b2, W3T, g3, b3,
        P1T, pg1, pb1, P2T, pg2, pb2, P3T, pb3, msa, out);
}